// Round 1
// baseline (1023.263 us; speedup 1.0000x reference)
//
#include <hip/hip_runtime.h>
#include <math.h>

#define B_ 8
#define L_ 4096
#define H_ 8
#define D_ 64
#define U_ 45
#define BH_ 64
#define NCH_ 64
#define NEG_ 1e30f

// ---------------- Kernel 1: M = max_s(QK_s) - sum_s(QK_s)/L ----------------
// grid: BH_ * (L_/4), block 256 (4 waves, 1 query per wave). lane = sample s.
__global__ __launch_bounds__(256) void k1_M(const float* __restrict__ Q,
                                            const float* __restrict__ K,
                                            const int* __restrict__ idx,
                                            float* __restrict__ M) {
  __shared__ float qs[4][64];
  int t = threadIdx.x;
  int w = t >> 6, lane = t & 63;
  int gid = blockIdx.x;
  int bh = gid / (L_ / 4);
  int lg = gid % (L_ / 4);
  int b = bh >> 3, h = bh & 7;
  int l = lg * 4 + w;

  // stage this wave's q row (lane = d) — same-wave producer/consumer, no barrier needed
  size_t qbase = (((size_t)b * L_ + l) * H_ + h) * (size_t)D_;
  qs[w][lane] = Q[qbase + lane];

  int s = lane;
  bool act = (s < U_);
  int j = 0;
  if (act) j = idx[l * U_ + s];
  const float4* kr = (const float4*)(K + (((size_t)b * L_ + j) * H_ + h) * (size_t)D_);
  const float4* qr = (const float4*)qs[w];
  float acc = 0.f;
#pragma unroll
  for (int d4 = 0; d4 < 16; ++d4) {
    float4 kv = kr[d4];   // per-lane 256B row gather (L2-resident)
    float4 qv = qr[d4];   // LDS broadcast
    acc += qv.x * kv.x + qv.y * kv.y + qv.z * kv.z + qv.w * kv.w;
  }
  float mv = act ? acc : -NEG_;
  float sv = act ? acc : 0.f;
#pragma unroll
  for (int off = 32; off; off >>= 1) {
    mv = fmaxf(mv, __shfl_xor(mv, off));
    sv += __shfl_xor(sv, off);
  }
  if (lane == 0) M[(size_t)bh * L_ + l] = mv - sv * (1.0f / (float)L_);
}

// ---------------- Kernel 2: top-45 per (b,h), iterative argmax ----------------
// grid BH_, block 256. Tie-break: smallest index (matches jax.lax.top_k).
__global__ __launch_bounds__(256) void k2_topk(const float* __restrict__ M,
                                               int* __restrict__ Mtop) {
  __shared__ float mv[L_];
  __shared__ float rv[4];
  __shared__ int ri[4];
  int bh = blockIdx.x;
  int t = threadIdx.x;
  int lane = t & 63, w = t >> 6;
  for (int i = t; i < L_; i += 256) mv[i] = M[(size_t)bh * L_ + i];
  __syncthreads();
  for (int it = 0; it < U_; ++it) {
    float bv = -NEG_;
    int bi = 0;
    for (int i = t; i < L_; i += 256) {
      float v = mv[i];
      if (v > bv) { bv = v; bi = i; }   // ascending scan -> strict '>' keeps smallest idx
    }
#pragma unroll
    for (int off = 32; off; off >>= 1) {
      float ov = __shfl_xor(bv, off);
      int oi = __shfl_xor(bi, off);
      if (ov > bv || (ov == bv && oi < bi)) { bv = ov; bi = oi; }
    }
    if (lane == 0) { rv[w] = bv; ri[w] = bi; }
    __syncthreads();
    if (t == 0) {
      float fv = rv[0];
      int fi = ri[0];
      for (int k = 1; k < 4; ++k)
        if (rv[k] > fv || (rv[k] == fv && ri[k] < fi)) { fv = rv[k]; fi = ri[k]; }
      Mtop[bh * 48 + it] = fi;
      mv[fi] = -NEG_;
    }
    __syncthreads();
  }
}

// ---------------- Kernel 3: cumsum(V) along L, write to out (B,H,L,D) ----------------
__global__ void k3a(const float* __restrict__ V, float* __restrict__ cpart) {
  int ch = blockIdx.x, bh = blockIdx.y;
  int b = bh >> 3, h = bh & 7, lane = threadIdx.x;
  float s = 0.f;
  size_t base = (((size_t)b * L_ + ch * 64) * H_ + h) * (size_t)D_ + lane;
  for (int i = 0; i < 64; ++i) s += V[base + (size_t)i * H_ * D_];
  cpart[((size_t)bh * NCH_ + ch) * 64 + lane] = s;
}
__global__ void k3b(float* __restrict__ cpart) {
  int bh = blockIdx.x, lane = threadIdx.x;
  float run = 0.f;
  for (int ch = 0; ch < NCH_; ++ch) {
    size_t p = ((size_t)bh * NCH_ + ch) * 64 + lane;
    float tv = cpart[p];
    cpart[p] = run;
    run += tv;
  }
}
__global__ void k3c(const float* __restrict__ V, const float* __restrict__ cpart,
                    float* __restrict__ out) {
  int ch = blockIdx.x, bh = blockIdx.y;
  int b = bh >> 3, h = bh & 7, lane = threadIdx.x;
  float run = cpart[((size_t)bh * NCH_ + ch) * 64 + lane];
  size_t ibase = (((size_t)b * L_ + ch * 64) * H_ + h) * (size_t)D_ + lane;
  size_t obase = ((size_t)bh * L_ + ch * 64) * 64 + lane;
  for (int i = 0; i < 64; ++i) {
    run += V[ibase + (size_t)i * H_ * D_];
    out[obase + (size_t)i * 64] = run;
  }
}

// ---------------- Kernel 4a: flash partials over key splits ----------------
// grid (S, BH_), block 256. Each block: keys [s*CHUNK, (s+1)*CHUNK) for all 45 top queries.
__global__ __launch_bounds__(256) void k4a(const float* __restrict__ Q,
                                           const float* __restrict__ K,
                                           const float* __restrict__ V,
                                           const int* __restrict__ Mtop,
                                           float* __restrict__ part, int CHUNK, int S) {
  __shared__ float KsT[64 * 65];      // [d][k], pad 65 -> conflict-free both ways
  __shared__ float Vs[64 * 64];       // [k][d]
  __shared__ float q_lds[U_ * 64];    // [u][d]
  __shared__ float p_lds[U_ * 64];    // [u][k]
  __shared__ int mt[48];
  int t = threadIdx.x, lane = t & 63, w = t >> 6;
  int s = blockIdx.x, bh = blockIdx.y;
  int b = bh >> 3, h = bh & 7;
  int k0 = s * CHUNK;

  if (t < U_) mt[t] = Mtop[bh * 48 + t];
  __syncthreads();
  int mmax = 0;
  for (int u = 0; u < U_; ++u) mmax = max(mmax, mt[u]);
  if (k0 > mmax) return;  // uniform: nothing in this split survives the causal mask

  // stage q rows for this wave's queries (u = w + 4i) — same-wave use only
  for (int u = w; u < U_; u += 4)
    q_lds[u * 64 + lane] = Q[(((size_t)b * L_ + mt[u]) * H_ + h) * (size_t)D_ + lane];

  float rm[12], rl[12], pacc[12];
#pragma unroll
  for (int i = 0; i < 12; ++i) { rm[i] = -NEG_; rl[i] = 0.f; pacc[i] = 0.f; }

  int nsub = CHUNK >> 6;
  for (int sub = 0; sub < nsub; ++sub) {
    int kk0 = k0 + (sub << 6);
    if (kk0 > mmax) break;  // uniform
    __syncthreads();        // previous PV done before restaging
    // stage 64 keys: wave w loads rows w+4i (coalesced), writes conflict-free
    for (int i2 = 0; i2 < 16; ++i2) {
      int kk = w + 4 * i2;
      size_t gb = (((size_t)b * L_ + kk0 + kk) * H_ + h) * (size_t)D_ + lane;
      KsT[lane * 65 + kk] = K[gb];
      Vs[kk * 64 + lane] = V[gb];
    }
    __syncthreads();

    // QK^T: lane = key, register-tiled over 12 queries
    float sc[12];
#pragma unroll
    for (int i = 0; i < 12; ++i) sc[i] = 0.f;
    for (int d = 0; d < 64; ++d) {
      float kv = KsT[d * 65 + lane];
#pragma unroll
      for (int i = 0; i < 12; ++i) {
        int u = w + 4 * i;
        if (u < U_) sc[i] += q_lds[u * 64 + d] * kv;
      }
    }
    // per-query online softmax over this 64-key subtile
#pragma unroll
    for (int i = 0; i < 12; ++i) {
      int u = w + 4 * i;
      if (u >= U_) continue;
      int m_u = mt[u];
      if (m_u < kk0) { p_lds[u * 64 + lane] = 0.f; continue; }  // fully masked subtile
      int k = kk0 + lane;
      bool act2 = (k <= m_u);
      float scs = sc[i] * 0.125f;
      float mval = act2 ? scs : -NEG_;
#pragma unroll
      for (int off = 32; off; off >>= 1) mval = fmaxf(mval, __shfl_xor(mval, off));
      float nm = fmaxf(rm[i], mval);
      float p = act2 ? __expf(scs - nm) : 0.f;
      float ps = p;
#pragma unroll
      for (int off = 32; off; off >>= 1) ps += __shfl_xor(ps, off);
      float sc_old = __expf(rm[i] - nm);
      rl[i] = rl[i] * sc_old + ps;
      rm[i] = nm;
      pacc[i] *= sc_old;
      p_lds[u * 64 + lane] = p;
    }
    // PV: lane = d, accumulate (same-wave p_lds rows -> no barrier needed)
    for (int k = 0; k < 64; ++k) {
      float vv = Vs[k * 64 + lane];
#pragma unroll
      for (int i = 0; i < 12; ++i) {
        int u = w + 4 * i;
        if (u < U_) pacc[i] += p_lds[u * 64 + k] * vv;
      }
    }
  }

  // write partial records {m, l, acc[64]} for u with mt[u] >= k0 (exactly what k4b reads)
#pragma unroll
  for (int i = 0; i < 12; ++i) {
    int u = w + 4 * i;
    if (u >= U_) continue;
    if (mt[u] < k0) continue;
    size_t pb = (((size_t)bh * U_ + u) * S + s) * 66;
    part[pb + 2 + lane] = pacc[i];
    if (lane == 0) { part[pb] = rm[i]; part[pb + 1] = rl[i]; }
  }
}

// ---------------- Kernel 4b: combine partials, scatter into out ----------------
// grid (U_, BH_), block 64 (lane = d)
__global__ void k4b(const float* __restrict__ part, const int* __restrict__ Mtop,
                    float* __restrict__ out, int CHUNK, int S) {
  int u = blockIdx.x, bh = blockIdx.y, lane = threadIdx.x;
  int m_u = Mtop[bh * 48 + u];
  int ns = m_u / CHUNK + 1;
  float gm = -NEG_, gl = 0.f, ga = 0.f;
  for (int s = 0; s < ns; ++s) {
    size_t pb = (((size_t)bh * U_ + u) * S + s) * 66;
    float ms = part[pb], ls = part[pb + 1], as = part[pb + 2 + lane];
    float nm = fmaxf(gm, ms);
    float w1 = __expf(gm - nm), w2 = __expf(ms - nm);
    ga = ga * w1 + as * w2;
    gl = gl * w1 + ls * w2;
    gm = nm;
  }
  out[((size_t)bh * L_ + m_u) * 64 + lane] = ga / gl;
}

extern "C" void kernel_launch(void* const* d_in, const int* in_sizes, int n_in,
                              void* d_out, int out_size, void* d_ws, size_t ws_size,
                              hipStream_t stream) {
  const float* Q = (const float*)d_in[0];
  const float* K = (const float*)d_in[1];
  const float* V = (const float*)d_in[2];
  const int* idx = (const int*)d_in[3];
  float* out = (float*)d_out;
  char* ws = (char*)d_ws;

  size_t offM = 0;                                   // BH_*L_ floats = 1 MiB
  size_t offT = offM + (size_t)BH_ * L_ * 4;         // 64*48 ints
  size_t offC = offT + (size_t)BH_ * 48 * 4;         // BH_*NCH_*64 floats = 1 MiB
  size_t offP = offC + (size_t)BH_ * NCH_ * 64 * 4;
  offP = (offP + 255) & ~(size_t)255;
  float* M = (float*)(ws + offM);
  int* Mtop = (int*)(ws + offT);
  float* cpart = (float*)(ws + offC);
  float* part = (float*)(ws + offP);

  size_t avail = (ws_size > offP) ? ws_size - offP : 0;
  int S = 64;
  while (S > 1 && (size_t)BH_ * U_ * (size_t)S * 66 * 4 > avail) S >>= 1;
  int CHUNK = L_ / S;

  k1_M<<<BH_ * (L_ / 4), 256, 0, stream>>>(Q, K, idx, M);
  k2_topk<<<BH_, 256, 0, stream>>>(M, Mtop);
  k3a<<<dim3(NCH_, BH_), 64, 0, stream>>>(V, cpart);
  k3b<<<BH_, 64, 0, stream>>>(cpart);
  k3c<<<dim3(NCH_, BH_), 64, 0, stream>>>(V, cpart, out);
  k4a<<<dim3(S, BH_), 256, 0, stream>>>(Q, K, V, Mtop, part, CHUNK, S);
  k4b<<<dim3(U_, BH_), 64, 0, stream>>>(part, Mtop, out, CHUNK, S);
}

// Round 2
// 752.954 us; speedup vs baseline: 1.3590x; 1.3590x over previous
//
#include <hip/hip_runtime.h>
#include <math.h>

#define B_ 8
#define L_ 4096
#define H_ 8
#define D_ 64
#define U_ 45
#define BH_ 64
#define NCH_ 64
#define NEG_ 1e30f

// ---------------- Kernel 1: M = max_s(QK_s) - sum_s(QK_s)/L ----------------
// grid: BH_ * (L_/4), block 256 (4 waves, 1 query per wave).
// Wave = 16 groups x 4 lanes; group g handles samples {g, g+16, g+32}.
// Within a group the 4 lanes read 4 consecutive 16B blocks of the K row ->
// exactly 1 cache line per group per load instruction (16 lines/instr vs 64
// for the lane=sample mapping). TA line-rate model: ~186 lines/query.
__global__ __launch_bounds__(256) void k1_M(const float* __restrict__ Q,
                                            const float* __restrict__ K,
                                            const int* __restrict__ idx,
                                            float* __restrict__ M) {
  __shared__ float qs[4][64];
  int t = threadIdx.x;
  int w = t >> 6, lane = t & 63;
  int gid = blockIdx.x;
  int bh = gid >> 10;          // / (L_/4)
  int lg = gid & 1023;
  int b = bh >> 3, h = bh & 7;
  int l = lg * 4 + w;

  // stage this wave's q row (lane = d) — same-wave producer/consumer
  size_t qbase = (((size_t)b * L_ + l) * H_ + h) * (size_t)D_;
  qs[w][lane] = Q[qbase + lane];

  int g = lane >> 2, r = lane & 3;
  const float4* qr = (const float4*)qs[w];

  float mv = -NEG_, sv = 0.f;
#pragma unroll
  for (int slot = 0; slot < 3; ++slot) {
    int s = g + (slot << 4);
    bool act = (s < U_);
    float acc = 0.f;
    if (act) {
      int j = idx[l * U_ + s];   // 4 lanes/group same addr -> broadcast
      const float4* kr = (const float4*)(K + (((size_t)b * L_ + j) * H_ + h) * (size_t)D_);
#pragma unroll
      for (int qq = 0; qq < 4; ++qq) {
        int f = r + (qq << 2);   // group's 4 lanes -> 1 contiguous 64B line
        float4 kv = kr[f];
        float4 qv = qr[f];
        acc += qv.x * kv.x + qv.y * kv.y + qv.z * kv.z + qv.w * kv.w;
      }
      acc += __shfl_xor(acc, 1);
      acc += __shfl_xor(acc, 2);
      mv = fmaxf(mv, acc);
      sv += acc;
    }
  }
  // reduce across the 16 groups (lanes within a group hold identical values)
#pragma unroll
  for (int off = 4; off < 64; off <<= 1) {
    mv = fmaxf(mv, __shfl_xor(mv, off));
    sv += __shfl_xor(sv, off);
  }
  if (lane == 0) M[(size_t)bh * L_ + l] = mv - sv * (1.0f / (float)L_);
}

// ---------------- Kernel 2: top-45 per (b,h), iterative argmax ----------------
// grid BH_, block 256. Tie-break: smallest index (matches jax.lax.top_k).
__global__ __launch_bounds__(256) void k2_topk(const float* __restrict__ M,
                                               int* __restrict__ Mtop) {
  __shared__ float mv[L_];
  __shared__ float rv[4];
  __shared__ int ri[4];
  int bh = blockIdx.x;
  int t = threadIdx.x;
  int lane = t & 63, w = t >> 6;
  for (int i = t; i < L_; i += 256) mv[i] = M[(size_t)bh * L_ + i];
  __syncthreads();
  for (int it = 0; it < U_; ++it) {
    float bv = -NEG_;
    int bi = 0;
    for (int i = t; i < L_; i += 256) {
      float v = mv[i];
      if (v > bv) { bv = v; bi = i; }   // ascending scan -> strict '>' keeps smallest idx
    }
#pragma unroll
    for (int off = 32; off; off >>= 1) {
      float ov = __shfl_xor(bv, off);
      int oi = __shfl_xor(bi, off);
      if (ov > bv || (ov == bv && oi < bi)) { bv = ov; bi = oi; }
    }
    if (lane == 0) { rv[w] = bv; ri[w] = bi; }
    __syncthreads();
    if (t == 0) {
      float fv = rv[0];
      int fi = ri[0];
      for (int k = 1; k < 4; ++k)
        if (rv[k] > fv || (rv[k] == fv && ri[k] < fi)) { fv = rv[k]; fi = ri[k]; }
      Mtop[bh * 48 + it] = fi;
      mv[fi] = -NEG_;
    }
    __syncthreads();
  }
}

// ---------------- Kernel 3: cumsum(V) along L, write to out (B,H,L,D) ----------------
__global__ void k3a(const float* __restrict__ V, float* __restrict__ cpart) {
  int ch = blockIdx.x, bh = blockIdx.y;
  int b = bh >> 3, h = bh & 7, lane = threadIdx.x;
  float s = 0.f;
  size_t base = (((size_t)b * L_ + ch * 64) * H_ + h) * (size_t)D_ + lane;
  for (int i = 0; i < 64; ++i) s += V[base + (size_t)i * H_ * D_];
  cpart[((size_t)bh * NCH_ + ch) * 64 + lane] = s;
}
__global__ void k3b(float* __restrict__ cpart) {
  int bh = blockIdx.x, lane = threadIdx.x;
  float run = 0.f;
  for (int ch = 0; ch < NCH_; ++ch) {
    size_t p = ((size_t)bh * NCH_ + ch) * 64 + lane;
    float tv = cpart[p];
    cpart[p] = run;
    run += tv;
  }
}
__global__ void k3c(const float* __restrict__ V, const float* __restrict__ cpart,
                    float* __restrict__ out) {
  int ch = blockIdx.x, bh = blockIdx.y;
  int b = bh >> 3, h = bh & 7, lane = threadIdx.x;
  float run = cpart[((size_t)bh * NCH_ + ch) * 64 + lane];
  size_t ibase = (((size_t)b * L_ + ch * 64) * H_ + h) * (size_t)D_ + lane;
  size_t obase = ((size_t)bh * L_ + ch * 64) * 64 + lane;
  for (int i = 0; i < 64; ++i) {
    run += V[ibase + (size_t)i * H_ * D_];
    out[obase + (size_t)i * 64] = run;
  }
}

// ---------------- Kernel 4a: flash partials over key splits ----------------
// grid (S, BH_), block 256. Each block: keys [s*CHUNK, (s+1)*CHUNK) for all 45 top queries.
__global__ __launch_bounds__(256) void k4a(const float* __restrict__ Q,
                                           const float* __restrict__ K,
                                           const float* __restrict__ V,
                                           const int* __restrict__ Mtop,
                                           float* __restrict__ part, int CHUNK, int S) {
  __shared__ float KsT[64 * 65];      // [d][k], pad 65 -> conflict-free both ways
  __shared__ float Vs[64 * 64];       // [k][d]
  __shared__ float q_lds[U_ * 64];    // [u][d]
  __shared__ float p_lds[U_ * 64];    // [u][k]
  __shared__ int mt[48];
  int t = threadIdx.x, lane = t & 63, w = t >> 6;
  int s = blockIdx.x, bh = blockIdx.y;
  int b = bh >> 3, h = bh & 7;
  int k0 = s * CHUNK;

  if (t < U_) mt[t] = Mtop[bh * 48 + t];
  __syncthreads();
  int mmax = 0;
  for (int u = 0; u < U_; ++u) mmax = max(mmax, mt[u]);
  if (k0 > mmax) return;  // uniform: nothing in this split survives the causal mask

  // stage q rows for this wave's queries (u = w + 4i) — same-wave use only
  for (int u = w; u < U_; u += 4)
    q_lds[u * 64 + lane] = Q[(((size_t)b * L_ + mt[u]) * H_ + h) * (size_t)D_ + lane];

  float rm[12], rl[12], pacc[12];
#pragma unroll
  for (int i = 0; i < 12; ++i) { rm[i] = -NEG_; rl[i] = 0.f; pacc[i] = 0.f; }

  int nsub = CHUNK >> 6;
  for (int sub = 0; sub < nsub; ++sub) {
    int kk0 = k0 + (sub << 6);
    if (kk0 > mmax) break;  // uniform
    __syncthreads();        // previous PV done before restaging
    // stage 64 keys: wave w loads rows w+4i (coalesced), writes conflict-free
    for (int i2 = 0; i2 < 16; ++i2) {
      int kk = w + 4 * i2;
      size_t gb = (((size_t)b * L_ + kk0 + kk) * H_ + h) * (size_t)D_ + lane;
      KsT[lane * 65 + kk] = K[gb];
      Vs[kk * 64 + lane] = V[gb];
    }
    __syncthreads();

    // QK^T: lane = key, register-tiled over 12 queries
    float sc[12];
#pragma unroll
    for (int i = 0; i < 12; ++i) sc[i] = 0.f;
    for (int d = 0; d < 64; ++d) {
      float kv = KsT[d * 65 + lane];
#pragma unroll
      for (int i = 0; i < 12; ++i) {
        int u = w + 4 * i;
        if (u < U_) sc[i] += q_lds[u * 64 + d] * kv;
      }
    }
    // per-query online softmax over this 64-key subtile
#pragma unroll
    for (int i = 0; i < 12; ++i) {
      int u = w + 4 * i;
      if (u >= U_) continue;
      int m_u = mt[u];
      if (m_u < kk0) { p_lds[u * 64 + lane] = 0.f; continue; }  // fully masked subtile
      int k = kk0 + lane;
      bool act2 = (k <= m_u);
      float scs = sc[i] * 0.125f;
      float mval = act2 ? scs : -NEG_;
#pragma unroll
      for (int off = 32; off; off >>= 1) mval = fmaxf(mval, __shfl_xor(mval, off));
      float nm = fmaxf(rm[i], mval);
      float p = act2 ? __expf(scs - nm) : 0.f;
      float ps = p;
#pragma unroll
      for (int off = 32; off; off >>= 1) ps += __shfl_xor(ps, off);
      float sc_old = __expf(rm[i] - nm);
      rl[i] = rl[i] * sc_old + ps;
      rm[i] = nm;
      pacc[i] *= sc_old;
      p_lds[u * 64 + lane] = p;
    }
    // PV: lane = d, accumulate (same-wave p_lds rows -> no barrier needed)
    for (int k = 0; k < 64; ++k) {
      float vv = Vs[k * 64 + lane];
#pragma unroll
      for (int i = 0; i < 12; ++i) {
        int u = w + 4 * i;
        if (u < U_) pacc[i] += p_lds[u * 64 + k] * vv;
      }
    }
  }

  // write partial records {m, l, acc[64]} for u with mt[u] >= k0 (exactly what k4b reads)
#pragma unroll
  for (int i = 0; i < 12; ++i) {
    int u = w + 4 * i;
    if (u >= U_) continue;
    if (mt[u] < k0) continue;
    size_t pb = (((size_t)bh * U_ + u) * S + s) * 66;
    part[pb + 2 + lane] = pacc[i];
    if (lane == 0) { part[pb] = rm[i]; part[pb + 1] = rl[i]; }
  }
}

// ---------------- Kernel 4b: combine partials, scatter into out ----------------
// grid (U_, BH_), block 64 (lane = d)
__global__ void k4b(const float* __restrict__ part, const int* __restrict__ Mtop,
                    float* __restrict__ out, int CHUNK, int S) {
  int u = blockIdx.x, bh = blockIdx.y, lane = threadIdx.x;
  int m_u = Mtop[bh * 48 + u];
  int ns = m_u / CHUNK + 1;
  float gm = -NEG_, gl = 0.f, ga = 0.f;
  for (int s = 0; s < ns; ++s) {
    size_t pb = (((size_t)bh * U_ + u) * S + s) * 66;
    float ms = part[pb], ls = part[pb + 1], as = part[pb + 2 + lane];
    float nm = fmaxf(gm, ms);
    float w1 = __expf(gm - nm), w2 = __expf(ms - nm);
    ga = ga * w1 + as * w2;
    gl = gl * w1 + ls * w2;
    gm = nm;
  }
  out[((size_t)bh * L_ + m_u) * 64 + lane] = ga / gl;
}

extern "C" void kernel_launch(void* const* d_in, const int* in_sizes, int n_in,
                              void* d_out, int out_size, void* d_ws, size_t ws_size,
                              hipStream_t stream) {
  const float* Q = (const float*)d_in[0];
  const float* K = (const float*)d_in[1];
  const float* V = (const float*)d_in[2];
  const int* idx = (const int*)d_in[3];
  float* out = (float*)d_out;
  char* ws = (char*)d_ws;

  size_t offM = 0;                                   // BH_*L_ floats = 1 MiB
  size_t offT = offM + (size_t)BH_ * L_ * 4;         // 64*48 ints
  size_t offC = offT + (size_t)BH_ * 48 * 4;         // BH_*NCH_*64 floats = 1 MiB
  size_t offP = offC + (size_t)BH_ * NCH_ * 64 * 4;
  offP = (offP + 255) & ~(size_t)255;
  float* M = (float*)(ws + offM);
  int* Mtop = (int*)(ws + offT);
  float* cpart = (float*)(ws + offC);
  float* part = (float*)(ws + offP);

  size_t avail = (ws_size > offP) ? ws_size - offP : 0;
  int S = 64;
  while (S > 1 && (size_t)BH_ * U_ * (size_t)S * 66 * 4 > avail) S >>= 1;
  int CHUNK = L_ / S;

  k1_M<<<BH_ * (L_ / 4), 256, 0, stream>>>(Q, K, idx, M);
  k2_topk<<<BH_, 256, 0, stream>>>(M, Mtop);
  k3a<<<dim3(NCH_, BH_), 64, 0, stream>>>(V, cpart);
  k3b<<<BH_, 64, 0, stream>>>(cpart);
  k3c<<<dim3(NCH_, BH_), 64, 0, stream>>>(V, cpart, out);
  k4a<<<dim3(S, BH_), 256, 0, stream>>>(Q, K, V, Mtop, part, CHUNK, S);
  k4b<<<dim3(U_, BH_), 64, 0, stream>>>(part, Mtop, out, CHUNK, S);
}